// Round 1
// baseline (251.128 us; speedup 1.0000x reference)
//
#include <hip/hip_runtime.h>
#include <math.h>

#define NELEC 10
#define NSPIN 2
#define NPER 5
#define DIM 3
#define NION 2
#define DP 32
#define NDENSE 64
#define NPERM 120
#define RS 324   // G row stride (words): the 5 selectable rows land on disjoint bank quads.
#define HTS 124  // HT row stride (words): reads 2 addrs/bank-quad (free, m136); writes 2/bank free.
#define KQ 16    // k-rows parked per quarter (R16: LDS occupancy split)

// Per-spin LDS pool, all regions coexist (R16: no stage-B overlay anymore):
//   s1e[160] @ 0, G[5][324] @ 160..1780, HTQ[16][124] @ 1780..3764
// Pool/spin = 15056 B -> block total ~30.3 KB -> 4 WGs/CU (vs 2 at the old 64 KB).
#define POOL_WORDS (160 + NPER * RS + KQ * HTS)

typedef float v2f __attribute__((ext_vector_type(2)));
typedef float v4f __attribute__((ext_vector_type(4)));

// Packed fp32 FMA (VOP3P), bit-identical to scalar v_fma pairs (R12-validated).
#define PK_FMA_LO(acc, hp, wp) \
    asm("v_pk_fma_f32 %0, %1, %2, %0 op_sel_hi:[1,0,1]" : "+v"(acc) : "v"(hp), "v"(wp))
#define PK_FMA_HI(acc, hp, wp) \
    asm("v_pk_fma_f32 %0, %1, %2, %0 op_sel:[0,1,0] op_sel_hi:[1,1,1]" : "+v"(acc) : "v"(hp), "v"(wp))

// tanh(x) = 1 - 2*rcp(exp(2x)+1): ~1-2 ulp, exact at saturation. Validated R5-R15.
__device__ __forceinline__ float fast_tanh(float x) {
    float e = __expf(2.0f * x);
    return 1.0f - 2.0f * __builtin_amdgcn_rcpf(e + 1.0f);
}

__device__ __forceinline__ unsigned pick_remove(unsigned& el, int d) {
    unsigned v = (el >> (4 * d)) & 0xFu;
    unsigned low = el & ((1u << (4 * d)) - 1u);
    el = low | ((el >> (4 * (d + 1))) << (4 * d));
    return v;
}

// ---------------- fused: one block per batch element, 4 waves = 2 spin-pairs ----------------
// Base = R13+R14 (100us). ONE change vs that (R16): stage-3 h-park/GEMM split into 4
// k-quarters so the HT region shrinks 64x124 -> 16x124 and coexists with G. LDS/block
// 64000 -> ~30300 B: occupancy limiter moves from LDS (2 WG/CU) to VGPR (4 WG/CU).
// Per-element arithmetic order is bit-identical: same cc order for h/hdot, same k order
// for vp accumulation, same PK_FMA macros. launch_bounds(256,4) pins VGPRs <= 128.
__global__ __launch_bounds__(256, 4) void antisym_fused(
    const float* __restrict__ elec_pos, const float* __restrict__ ion_pos,
    const float* __restrict__ bf_w, const float* __restrict__ bf_b,
    const float* __restrict__ w0, const float* __restrict__ b0,
    const float* __restrict__ w1, const float* __restrict__ b1,
    const float* __restrict__ w2, const float* __restrict__ jk,
    float* __restrict__ out, int B)
{
    const int b = blockIdx.x;
    const int t = threadIdx.x;
    const int s = t >> 7;                   // spin: waves 0-1 -> 0, waves 2-3 -> 1
    const int ts = t & 127;                 // thread within the spin-pair
    const int wave = (t >> 6) & 1;          // wave within the spin-pair
    const int lane = t & 63;

    __shared__ __align__(16) float pool[NSPIN][POOL_WORDS];   // 2 x 15056 B
    __shared__ double red_h[NSPIN][2];
    __shared__ double red_j[NSPIN][2];
    __shared__ float jterm[2 * NELEC];

    float* s1e = pool[s];                                     // [160]
    #define GROW(j)   (pool[s] + 160 + (j) * RS)              // G[j][.]
    #define HTQROW(k) (pool[s] + 160 + NPER * RS + (k) * HTS) // HTQ[k][.], k in [0,16)

    // ---- stage 1: stream_1e = tanh(feats @ bf_w + bf_b), this spin's 5 electrons ----
    const float* ep = elec_pos + (b * NELEC + s * NPER) * DIM;
    const float i0x = ion_pos[0], i0y = ion_pos[1], i0z = ion_pos[2];
    const float i1x = ion_pos[3], i1y = ion_pos[4], i1z = ion_pos[5];
    for (int idx = ts; idx < NPER * DP; idx += 128) {
        int j = idx >> 5, c = idx & 31;
        float ex = ep[j * 3 + 0], ey = ep[j * 3 + 1], ez = ep[j * 3 + 2];
        float dx0 = ex - i0x, dy0 = ey - i0y, dz0 = ez - i0z;
        float dx1 = ex - i1x, dy1 = ey - i1y, dz1 = ez - i1z;
        float n0 = sqrtf(dx0 * dx0 + dy0 * dy0 + dz0 * dz0);
        float n1 = sqrtf(dx1 * dx1 + dy1 * dy1 + dz1 * dz1);
        float acc = bf_b[c];
        acc += dx0 * bf_w[0 * DP + c];
        acc += dy0 * bf_w[1 * DP + c];
        acc += dz0 * bf_w[2 * DP + c];
        acc += dx1 * bf_w[3 * DP + c];
        acc += dy1 * bf_w[4 * DP + c];
        acc += dz1 * bf_w[5 * DP + c];
        acc += n0 * bf_w[6 * DP + c];
        acc += n1 * bf_w[7 * DP + c];
        s1e[idx] = fast_tanh(acc);
    }
    // jastrow terms (combine's exact per-term math; summed e-major by t0 later)
    if (t < 2 * NELEC) {
        int e = t >> 1, ion = t & 1;
        const float* epb = elec_pos + b * NELEC * DIM;
        float ex = epb[e * 3 + 0], ey = epb[e * 3 + 1], ez = epb[e * 3 + 2];
        float ix = ion_pos[ion * 3 + 0], iy = ion_pos[ion * 3 + 1], iz = ion_pos[ion * 3 + 2];
        float dx = ex - ix, dy = ey - iy, dz = ez - iz;
        jterm[t] = jk[ion] * sqrtf(dx * dx + dy * dy + dz * dz);
    }
    __syncthreads();

    // ---- stage 2: G[j][i*64+c] = s1e[j][:] @ w0[s][32i:32i+32, c] ----
    // Slice-outer with wcol[32] in registers (R14): 96 global loads/wave.
    const float* w0s = w0 + s * (NPER * DP) * NDENSE;   // [160][64]
    #pragma unroll
    for (int m = 0; m < 3; m++) {
        const int i = wave + 2 * m;         // wave0: i=0,2,4  wave1: i=1,3 (m=2 skipped)
        if (i < NPER) {                     // wave-uniform branch
            float wcol[DP];
            #pragma unroll
            for (int k = 0; k < DP; k++) wcol[k] = w0s[(i * DP + k) * NDENSE + lane];
            #pragma unroll
            for (int j = 0; j < NPER; j++) {
                float acc = 0.f;
                #pragma unroll
                for (int q = 0; q < 8; q++) {
                    float4 sv = *(const float4*)(s1e + j * DP + q * 4);   // LDS broadcast
                    acc += sv.x * wcol[q * 4 + 0];
                    acc += sv.y * wcol[q * 4 + 1];
                    acc += sv.z * wcol[q * 4 + 2];
                    acc += sv.w * wcol[q * 4 + 3];
                }
                GROW(j)[i * NDENSE + lane] = acc;
            }
        }
    }
    __syncthreads();

    const float* b0s = b0 + s * NDENSE;
    const float* w2s = w2 + s * NDENSE;     // w2 is [s][64][1]
    const float* b1s = b1 + s * NDENSE;
    const float* w1s = w1 + s * NDENSE * NDENSE;

    // ---- stage 3: lane = perm (phase 1) interleaved with 8x8-tile GEMM (phase 2),
    //      split into 4 k-quarters so only 16 HT rows are ever parked at once ----
    const int pid = wave * 60 + lane;
    float sign = 0.f;
    int p0 = 0, p1 = 0, p2 = 0, p3 = 0, p4 = 0;
    if (lane < 60) {
        int p = pid;
        unsigned el = 0x43210u;
        int d0 = p / 24; p -= d0 * 24;
        int d1 = p / 6;  p -= d1 * 6;
        int d2 = p / 2;  p -= d2 * 2;
        int d3 = p;
        p0 = pick_remove(el, d0);
        p1 = pick_remove(el, d1);
        p2 = pick_remove(el, d2);
        p3 = pick_remove(el, d3);
        p4 = el & 0xF;
        sign = ((d0 + d1 + d2 + d3) & 1) ? -1.f : 1.f;
    }
    const float* g0 = GROW(p0) + 0 * NDENSE;
    const float* g1 = GROW(p1) + 1 * NDENSE;
    const float* g2 = GROW(p2) + 2 * NDENSE;
    const float* g3 = GROW(p3) + 3 * NDENSE;
    const float* g4 = GROW(p4) + 4 * NDENSE;

    const int pg = lane >> 3, jg = lane & 7;
    const int pb = wave ? (56 + 8 * pg) : (8 * pg);
    const float* wgp = w1s + 8 * jg;        // this lane's j-octet in w1 row k

    v2f vp[4][8];
    #pragma unroll
    for (int ip = 0; ip < 4; ip++)
        #pragma unroll
        for (int r = 0; r < 8; r++) vp[ip][r] = (v2f)(0.f);

    float hdot = 0.f;

    for (int qq = 0; qq < 4; qq++) {
        // phase 1 quarter: h for k = 16*qq .. 16*qq+15 (same cc order as before)
        float hq[KQ];                       // constant-indexed -> VGPR-resident
        #pragma unroll
        for (int c = 0; c < 4; c++) {
            const int cc = qq * 4 + c;
            float4 a = *(const float4*)(b0s + cc * 4);                    // uniform
            float4 q;
            q = *(const float4*)(g0 + cc * 4); a.x += q.x; a.y += q.y; a.z += q.z; a.w += q.w;
            q = *(const float4*)(g1 + cc * 4); a.x += q.x; a.y += q.y; a.z += q.z; a.w += q.w;
            q = *(const float4*)(g2 + cc * 4); a.x += q.x; a.y += q.y; a.z += q.z; a.w += q.w;
            q = *(const float4*)(g3 + cc * 4); a.x += q.x; a.y += q.y; a.z += q.z; a.w += q.w;
            q = *(const float4*)(g4 + cc * 4); a.x += q.x; a.y += q.y; a.z += q.z; a.w += q.w;
            float t0 = fast_tanh(a.x), t1 = fast_tanh(a.y), t2 = fast_tanh(a.z), t3 = fast_tanh(a.w);
            hq[c * 4 + 0] = t0; hq[c * 4 + 1] = t1; hq[c * 4 + 2] = t2; hq[c * 4 + 3] = t3;
            hdot += t0 * w2s[cc * 4 + 0] + t1 * w2s[cc * 4 + 1]
                  + t2 * w2s[cc * 4 + 2] + t3 * w2s[cc * 4 + 3];
        }

        // park this quarter transposed: HTQ[kk][pid] (b32, consecutive pids -> free)
        if (lane < 60) {
            #pragma unroll
            for (int kk = 0; kk < KQ; kk++) HTQROW(kk)[pid] = hq[kk];
        }
        __syncthreads();                    // HTQ visible to both waves

        // phase 2 quarter: accumulate 16 k-steps of V[120x64] = H @ W1 (same k order)
        v4f ha_n = *(const v4f*)(&HTQROW(0)[pb]);
        v4f hb_n = *(const v4f*)(&HTQROW(0)[pb + 4]);
        v4f wa_n = *(const v4f*)(wgp + (qq * KQ) * NDENSE);
        v4f wb_n = *(const v4f*)(wgp + (qq * KQ) * NDENSE + 4);
        #pragma unroll 4
        for (int kk = 0; kk < KQ; kk++) {
            const v4f ha = ha_n, hb = hb_n, wa = wa_n, wb = wb_n;
            if (kk + 1 < KQ) {              // R10-validated k+1 prefetch (per quarter)
                ha_n = *(const v4f*)(&HTQROW(kk + 1)[pb]);
                hb_n = *(const v4f*)(&HTQROW(kk + 1)[pb + 4]);
                wa_n = *(const v4f*)(wgp + (qq * KQ + kk + 1) * NDENSE);
                wb_n = *(const v4f*)(wgp + (qq * KQ + kk + 1) * NDENSE + 4);
            }
            v2f hp[4] = {ha.xy, ha.zw, hb.xy, hb.zw};   // perm pairs
            v2f wp[4] = {wa.xy, wa.zw, wb.xy, wb.zw};   // j pairs
            #pragma unroll
            for (int ip = 0; ip < 4; ip++) {
                PK_FMA_LO(vp[ip][0], hp[ip], wp[0]);
                PK_FMA_HI(vp[ip][1], hp[ip], wp[0]);
                PK_FMA_LO(vp[ip][2], hp[ip], wp[1]);
                PK_FMA_HI(vp[ip][3], hp[ip], wp[1]);
                PK_FMA_LO(vp[ip][4], hp[ip], wp[2]);
                PK_FMA_HI(vp[ip][5], hp[ip], wp[2]);
                PK_FMA_LO(vp[ip][6], hp[ip], wp[3]);
                PK_FMA_HI(vp[ip][7], hp[ip], wp[3]);
            }
        }
        __syncthreads();                    // HTQ reads done before next quarter's park
    }

    double dvh = (double)(sign * hdot);     // sign=0 for lanes 60-63
    #pragma unroll
    for (int off = 32; off > 0; off >>= 1) dvh += __shfl_down(dvh, off, 64);
    if (lane == 0) red_h[s][wave] = dvh;

    // epilogue: lanesum = sum_i sgn_i * sum_r tanh(v[i][r]+b1[j]) * w2[j]
    float4 b1a = *(const float4*)(b1s + 8 * jg);
    float4 b1b = *(const float4*)(b1s + 8 * jg + 4);
    float4 w2a = *(const float4*)(w2s + 8 * jg);
    float4 w2b = *(const float4*)(w2s + 8 * jg + 4);
    const float b1v[8] = {b1a.x, b1a.y, b1a.z, b1a.w, b1b.x, b1b.y, b1b.z, b1b.w};
    const float w2v[8] = {w2a.x, w2a.y, w2a.z, w2a.w, w2b.x, w2b.y, w2b.z, w2b.w};

    float lanesum = 0.f;
    #pragma unroll
    for (int i = 0; i < 8; i++) {
        int p = pb + i;                      // Lehmer parity
        int d0 = p / 24;  int r0 = p - 24 * d0;
        int d1 = r0 / 6;  int r1 = r0 - 6 * d1;
        int d2 = r1 >> 1; int d3 = r1 & 1;
        float sgn = ((d0 + d1 + d2 + d3) & 1) ? -1.f : 1.f;
        if (wave == 1 && pg == 0) sgn = 0.f; // duplicate tile (perms 56-63)
        float si = 0.f;
        #pragma unroll
        for (int r = 0; r < 8; r++) {
            float vir = (i & 1) ? vp[i >> 1][r].y : vp[i >> 1][r].x;
            si = fmaf(fast_tanh(vir + b1v[r]), w2v[r], si);
        }
        lanesum = fmaf(sgn, si, lanesum);
    }

    double dvj = (double)lanesum;
    #pragma unroll
    for (int off = 32; off > 0; off >>= 1) dvj += __shfl_down(dvj, off, 64);
    if (lane == 0) red_j[s][wave] = dvj;
    __syncthreads();

    // ---- inline combine (R13-validated) ----
    if (t == 0) {
        float ps0 = (float)((red_h[0][0] + red_h[0][1]) + (red_j[0][0] + red_j[0][1]));
        float ps1 = (float)((red_h[1][0] + red_h[1][1]) + (red_j[1][0] + red_j[1][1]));
        float jas = 0.f;
        #pragma unroll
        for (int i = 0; i < 2 * NELEC; i++) jas += jterm[i];
        out[b] = logf(fabsf(ps0 * ps1)) - jas;
    }
    // b2 omitted: sum_p sign_p = 0 kills it exactly.
}

extern "C" void kernel_launch(void* const* d_in, const int* in_sizes, int n_in,
                              void* d_out, int out_size, void* d_ws, size_t ws_size,
                              hipStream_t stream) {
    const float* elec_pos = (const float*)d_in[0];
    const float* ion_pos  = (const float*)d_in[1];
    const float* bf_w     = (const float*)d_in[2];
    const float* bf_b     = (const float*)d_in[3];
    const float* w0       = (const float*)d_in[4];
    const float* b0       = (const float*)d_in[5];
    const float* w1       = (const float*)d_in[6];
    const float* b1       = (const float*)d_in[7];
    const float* w2       = (const float*)d_in[8];
    const float* jk       = (const float*)d_in[10];
    float* out = (float*)d_out;

    const int B = in_sizes[0] / (NELEC * DIM);   // 2048

    hipLaunchKernelGGL(antisym_fused,
                       dim3(B), dim3(256), 0, stream,
                       elec_pos, ion_pos, bf_w, bf_b, w0, b0, w1, b1, w2, jk, out, B);
}

// Round 2
// 162.087 us; speedup vs baseline: 1.5493x; 1.5493x over previous
//
#include <hip/hip_runtime.h>
#include <math.h>

#define NELEC 10
#define NSPIN 2
#define NPER 5
#define DIM 3
#define NION 2
#define DP 32
#define NDENSE 64
#define NPERM 120
#define RS 324   // G row stride (words): the 5 selectable rows land on disjoint bank quads.
#define HTS 124  // HT row stride (words): reads 2 addrs/bank-quad (free, m136); writes 2/bank free.
#define KQ 16    // k-rows parked per quarter (R16/R17: LDS occupancy split)

// Per-spin LDS pool, all regions coexist:
//   s1e[160] @ 0, G[5][324] @ 160..1780, HTQ[16][124] @ 1780..3764
// Pool/spin = 15056 B -> block total ~30.3 KB -> 5 WGs/CU by LDS (VGPR tier decides: 4).
#define POOL_WORDS (160 + NPER * RS + KQ * HTS)

typedef float v2f __attribute__((ext_vector_type(2)));
typedef float v4f __attribute__((ext_vector_type(4)));

// Packed fp32 FMA (VOP3P), bit-identical to scalar v_fma pairs (R12-validated).
#define PK_FMA_LO(acc, hp, wp) \
    asm("v_pk_fma_f32 %0, %1, %2, %0 op_sel_hi:[1,0,1]" : "+v"(acc) : "v"(hp), "v"(wp))
#define PK_FMA_HI(acc, hp, wp) \
    asm("v_pk_fma_f32 %0, %1, %2, %0 op_sel:[0,1,0] op_sel_hi:[1,1,1]" : "+v"(acc) : "v"(hp), "v"(wp))

// tanh(x) = 1 - 2*rcp(exp(2x)+1): ~1-2 ulp, exact at saturation. Validated R5-R15.
__device__ __forceinline__ float fast_tanh(float x) {
    float e = __expf(2.0f * x);
    return 1.0f - 2.0f * __builtin_amdgcn_rcpf(e + 1.0f);
}

__device__ __forceinline__ unsigned pick_remove(unsigned& el, int d) {
    unsigned v = (el >> (4 * d)) & 0xFu;
    unsigned low = el & ((1u << (4 * d)) - 1u);
    el = low | ((el >> (4 * (d + 1))) << (4 * d));
    return v;
}

// ---------------- fused: one block per batch element, 4 waves = 2 spin-pairs ----------------
// R17 = R16's LDS split with the register-tier bug fixed. R16's launch_bounds(256,4)
// (-> amdgpu-waves-per-eu min=4) made the backend chase the 64-VGPR/8-wave tier and
// spill vp[4][8] (600 MB of scratch traffic/dispatch, 100 -> 192us). Fix:
//   - launch_bounds(256,1): R13's known-good allocator behavior (116 VGPRs)
//   - amdgpu_num_vgpr(128): hard MAX cap so the allocator can't overshoot tiers
//   - hq[16] staging array deleted: h written straight to LDS as produced (bit-identical)
//   - manual k+1 prefetch dropped: 16 fewer live VGPRs; TLP at 16 waves/CU covers LDS
//     latency, and "#pragma unroll 4" still exposes ILP.
// Per-element arithmetic order is bit-identical to R13: same cc order for h/hdot,
// same k order for vp accumulation, same PK_FMA macros.
__global__ __launch_bounds__(256, 1) __attribute__((amdgpu_num_vgpr(128)))
void antisym_fused(
    const float* __restrict__ elec_pos, const float* __restrict__ ion_pos,
    const float* __restrict__ bf_w, const float* __restrict__ bf_b,
    const float* __restrict__ w0, const float* __restrict__ b0,
    const float* __restrict__ w1, const float* __restrict__ b1,
    const float* __restrict__ w2, const float* __restrict__ jk,
    float* __restrict__ out, int B)
{
    const int b = blockIdx.x;
    const int t = threadIdx.x;
    const int s = t >> 7;                   // spin: waves 0-1 -> 0, waves 2-3 -> 1
    const int ts = t & 127;                 // thread within the spin-pair
    const int wave = (t >> 6) & 1;          // wave within the spin-pair
    const int lane = t & 63;

    __shared__ __align__(16) float pool[NSPIN][POOL_WORDS];   // 2 x 15056 B
    __shared__ double red_h[NSPIN][2];
    __shared__ double red_j[NSPIN][2];
    __shared__ float jterm[2 * NELEC];

    float* s1e = pool[s];                                     // [160]
    #define GROW(j)   (pool[s] + 160 + (j) * RS)              // G[j][.]
    #define HTQROW(k) (pool[s] + 160 + NPER * RS + (k) * HTS) // HTQ[k][.], k in [0,16)

    // ---- stage 1: stream_1e = tanh(feats @ bf_w + bf_b), this spin's 5 electrons ----
    const float* ep = elec_pos + (b * NELEC + s * NPER) * DIM;
    const float i0x = ion_pos[0], i0y = ion_pos[1], i0z = ion_pos[2];
    const float i1x = ion_pos[3], i1y = ion_pos[4], i1z = ion_pos[5];
    for (int idx = ts; idx < NPER * DP; idx += 128) {
        int j = idx >> 5, c = idx & 31;
        float ex = ep[j * 3 + 0], ey = ep[j * 3 + 1], ez = ep[j * 3 + 2];
        float dx0 = ex - i0x, dy0 = ey - i0y, dz0 = ez - i0z;
        float dx1 = ex - i1x, dy1 = ey - i1y, dz1 = ez - i1z;
        float n0 = sqrtf(dx0 * dx0 + dy0 * dy0 + dz0 * dz0);
        float n1 = sqrtf(dx1 * dx1 + dy1 * dy1 + dz1 * dz1);
        float acc = bf_b[c];
        acc += dx0 * bf_w[0 * DP + c];
        acc += dy0 * bf_w[1 * DP + c];
        acc += dz0 * bf_w[2 * DP + c];
        acc += dx1 * bf_w[3 * DP + c];
        acc += dy1 * bf_w[4 * DP + c];
        acc += dz1 * bf_w[5 * DP + c];
        acc += n0 * bf_w[6 * DP + c];
        acc += n1 * bf_w[7 * DP + c];
        s1e[idx] = fast_tanh(acc);
    }
    // jastrow terms (combine's exact per-term math; summed e-major by t0 later)
    if (t < 2 * NELEC) {
        int e = t >> 1, ion = t & 1;
        const float* epb = elec_pos + b * NELEC * DIM;
        float ex = epb[e * 3 + 0], ey = epb[e * 3 + 1], ez = epb[e * 3 + 2];
        float ix = ion_pos[ion * 3 + 0], iy = ion_pos[ion * 3 + 1], iz = ion_pos[ion * 3 + 2];
        float dx = ex - ix, dy = ey - iy, dz = ez - iz;
        jterm[t] = jk[ion] * sqrtf(dx * dx + dy * dy + dz * dz);
    }
    __syncthreads();

    // ---- stage 2: G[j][i*64+c] = s1e[j][:] @ w0[s][32i:32i+32, c] ----
    // Slice-outer with wcol[32] in registers (R14): 96 global loads/wave.
    const float* w0s = w0 + s * (NPER * DP) * NDENSE;   // [160][64]
    #pragma unroll
    for (int m = 0; m < 3; m++) {
        const int i = wave + 2 * m;         // wave0: i=0,2,4  wave1: i=1,3 (m=2 skipped)
        if (i < NPER) {                     // wave-uniform branch
            float wcol[DP];
            #pragma unroll
            for (int k = 0; k < DP; k++) wcol[k] = w0s[(i * DP + k) * NDENSE + lane];
            #pragma unroll
            for (int j = 0; j < NPER; j++) {
                float acc = 0.f;
                #pragma unroll
                for (int q = 0; q < 8; q++) {
                    float4 sv = *(const float4*)(s1e + j * DP + q * 4);   // LDS broadcast
                    acc += sv.x * wcol[q * 4 + 0];
                    acc += sv.y * wcol[q * 4 + 1];
                    acc += sv.z * wcol[q * 4 + 2];
                    acc += sv.w * wcol[q * 4 + 3];
                }
                GROW(j)[i * NDENSE + lane] = acc;
            }
        }
    }
    __syncthreads();

    const float* b0s = b0 + s * NDENSE;
    const float* w2s = w2 + s * NDENSE;     // w2 is [s][64][1]
    const float* b1s = b1 + s * NDENSE;
    const float* w1s = w1 + s * NDENSE * NDENSE;

    // ---- stage 3: lane = perm (phase 1) interleaved with 8x8-tile GEMM (phase 2),
    //      split into 4 k-quarters so only 16 HT rows are ever parked at once ----
    const int pid = wave * 60 + lane;
    float sign = 0.f;
    int p0 = 0, p1 = 0, p2 = 0, p3 = 0, p4 = 0;
    if (lane < 60) {
        int p = pid;
        unsigned el = 0x43210u;
        int d0 = p / 24; p -= d0 * 24;
        int d1 = p / 6;  p -= d1 * 6;
        int d2 = p / 2;  p -= d2 * 2;
        int d3 = p;
        p0 = pick_remove(el, d0);
        p1 = pick_remove(el, d1);
        p2 = pick_remove(el, d2);
        p3 = pick_remove(el, d3);
        p4 = el & 0xF;
        sign = ((d0 + d1 + d2 + d3) & 1) ? -1.f : 1.f;
    }
    const float* g0 = GROW(p0) + 0 * NDENSE;
    const float* g1 = GROW(p1) + 1 * NDENSE;
    const float* g2 = GROW(p2) + 2 * NDENSE;
    const float* g3 = GROW(p3) + 3 * NDENSE;
    const float* g4 = GROW(p4) + 4 * NDENSE;

    const int pg = lane >> 3, jg = lane & 7;
    const int pb = wave ? (56 + 8 * pg) : (8 * pg);
    const float* wgp = w1s + 8 * jg;        // this lane's j-octet in w1 row k

    v2f vp[4][8];
    #pragma unroll
    for (int ip = 0; ip < 4; ip++)
        #pragma unroll
        for (int r = 0; r < 8; r++) vp[ip][r] = (v2f)(0.f);

    float hdot = 0.f;

    for (int qq = 0; qq < 4; qq++) {
        // phase 1 quarter: h for k = 16*qq .. 16*qq+15, written straight to HTQ
        // (no hq[] staging array -> 16 fewer live VGPRs; bit-identical values/order)
        #pragma unroll
        for (int c = 0; c < 4; c++) {
            const int cc = qq * 4 + c;
            float4 a = *(const float4*)(b0s + cc * 4);                    // uniform
            float4 q;
            q = *(const float4*)(g0 + cc * 4); a.x += q.x; a.y += q.y; a.z += q.z; a.w += q.w;
            q = *(const float4*)(g1 + cc * 4); a.x += q.x; a.y += q.y; a.z += q.z; a.w += q.w;
            q = *(const float4*)(g2 + cc * 4); a.x += q.x; a.y += q.y; a.z += q.z; a.w += q.w;
            q = *(const float4*)(g3 + cc * 4); a.x += q.x; a.y += q.y; a.z += q.z; a.w += q.w;
            q = *(const float4*)(g4 + cc * 4); a.x += q.x; a.y += q.y; a.z += q.z; a.w += q.w;
            float t0 = fast_tanh(a.x), t1 = fast_tanh(a.y), t2 = fast_tanh(a.z), t3 = fast_tanh(a.w);
            if (lane < 60) {
                HTQROW(c * 4 + 0)[pid] = t0;   // b32 writes, consecutive pids -> free
                HTQROW(c * 4 + 1)[pid] = t1;
                HTQROW(c * 4 + 2)[pid] = t2;
                HTQROW(c * 4 + 3)[pid] = t3;
            }
            hdot += t0 * w2s[cc * 4 + 0] + t1 * w2s[cc * 4 + 1]
                  + t2 * w2s[cc * 4 + 2] + t3 * w2s[cc * 4 + 3];
        }
        __syncthreads();                    // HTQ visible to both waves

        // phase 2 quarter: accumulate 16 k-steps of V[120x64] = H @ W1 (same k order)
        #pragma unroll 4
        for (int kk = 0; kk < KQ; kk++) {
            const v4f ha = *(const v4f*)(&HTQROW(kk)[pb]);
            const v4f hb = *(const v4f*)(&HTQROW(kk)[pb + 4]);
            const v4f wa = *(const v4f*)(wgp + (qq * KQ + kk) * NDENSE);
            const v4f wb = *(const v4f*)(wgp + (qq * KQ + kk) * NDENSE + 4);
            v2f hp[4] = {ha.xy, ha.zw, hb.xy, hb.zw};   // perm pairs
            v2f wp[4] = {wa.xy, wa.zw, wb.xy, wb.zw};   // j pairs
            #pragma unroll
            for (int ip = 0; ip < 4; ip++) {
                PK_FMA_LO(vp[ip][0], hp[ip], wp[0]);
                PK_FMA_HI(vp[ip][1], hp[ip], wp[0]);
                PK_FMA_LO(vp[ip][2], hp[ip], wp[1]);
                PK_FMA_HI(vp[ip][3], hp[ip], wp[1]);
                PK_FMA_LO(vp[ip][4], hp[ip], wp[2]);
                PK_FMA_HI(vp[ip][5], hp[ip], wp[2]);
                PK_FMA_LO(vp[ip][6], hp[ip], wp[3]);
                PK_FMA_HI(vp[ip][7], hp[ip], wp[3]);
            }
        }
        __syncthreads();                    // HTQ reads done before next quarter's park
    }

    double dvh = (double)(sign * hdot);     // sign=0 for lanes 60-63
    #pragma unroll
    for (int off = 32; off > 0; off >>= 1) dvh += __shfl_down(dvh, off, 64);
    if (lane == 0) red_h[s][wave] = dvh;

    // epilogue: lanesum = sum_i sgn_i * sum_r tanh(v[i][r]+b1[j]) * w2[j]
    float4 b1a = *(const float4*)(b1s + 8 * jg);
    float4 b1b = *(const float4*)(b1s + 8 * jg + 4);
    float4 w2a = *(const float4*)(w2s + 8 * jg);
    float4 w2b = *(const float4*)(w2s + 8 * jg + 4);
    const float b1v[8] = {b1a.x, b1a.y, b1a.z, b1a.w, b1b.x, b1b.y, b1b.z, b1b.w};
    const float w2v[8] = {w2a.x, w2a.y, w2a.z, w2a.w, w2b.x, w2b.y, w2b.z, w2b.w};

    float lanesum = 0.f;
    #pragma unroll
    for (int i = 0; i < 8; i++) {
        int p = pb + i;                      // Lehmer parity
        int d0 = p / 24;  int r0 = p - 24 * d0;
        int d1 = r0 / 6;  int r1 = r0 - 6 * d1;
        int d2 = r1 >> 1; int d3 = r1 & 1;
        float sgn = ((d0 + d1 + d2 + d3) & 1) ? -1.f : 1.f;
        if (wave == 1 && pg == 0) sgn = 0.f; // duplicate tile (perms 56-63)
        float si = 0.f;
        #pragma unroll
        for (int r = 0; r < 8; r++) {
            float vir = (i & 1) ? vp[i >> 1][r].y : vp[i >> 1][r].x;
            si = fmaf(fast_tanh(vir + b1v[r]), w2v[r], si);
        }
        lanesum = fmaf(sgn, si, lanesum);
    }

    double dvj = (double)lanesum;
    #pragma unroll
    for (int off = 32; off > 0; off >>= 1) dvj += __shfl_down(dvj, off, 64);
    if (lane == 0) red_j[s][wave] = dvj;
    __syncthreads();

    // ---- inline combine (R13-validated) ----
    if (t == 0) {
        float ps0 = (float)((red_h[0][0] + red_h[0][1]) + (red_j[0][0] + red_j[0][1]));
        float ps1 = (float)((red_h[1][0] + red_h[1][1]) + (red_j[1][0] + red_j[1][1]));
        float jas = 0.f;
        #pragma unroll
        for (int i = 0; i < 2 * NELEC; i++) jas += jterm[i];
        out[b] = logf(fabsf(ps0 * ps1)) - jas;
    }
    // b2 omitted: sum_p sign_p = 0 kills it exactly.
}

extern "C" void kernel_launch(void* const* d_in, const int* in_sizes, int n_in,
                              void* d_out, int out_size, void* d_ws, size_t ws_size,
                              hipStream_t stream) {
    const float* elec_pos = (const float*)d_in[0];
    const float* ion_pos  = (const float*)d_in[1];
    const float* bf_w     = (const float*)d_in[2];
    const float* bf_b     = (const float*)d_in[3];
    const float* w0       = (const float*)d_in[4];
    const float* b0       = (const float*)d_in[5];
    const float* w1       = (const float*)d_in[6];
    const float* b1       = (const float*)d_in[7];
    const float* w2       = (const float*)d_in[8];
    const float* jk       = (const float*)d_in[10];
    float* out = (float*)d_out;

    const int B = in_sizes[0] / (NELEC * DIM);   // 2048

    hipLaunchKernelGGL(antisym_fused,
                       dim3(B), dim3(256), 0, stream,
                       elec_pos, ion_pos, bf_w, bf_b, w0, b0, w1, b1, w2, jk, out, B);
}

// Round 3
// 160.504 us; speedup vs baseline: 1.5646x; 1.0099x over previous
//
#include <hip/hip_runtime.h>
#include <math.h>

#define NELEC 10
#define NSPIN 2
#define NPER 5
#define DIM 3
#define NION 2
#define DP 32
#define NDENSE 64
#define NPERM 120
#define RS 324   // G row stride (words): the 5 selectable rows land on disjoint bank quads.
#define HTS 124  // HT row stride (words): reads 2 addrs/bank-quad (free, m136); writes 2/bank free.
#define KQ 16    // k-rows parked per quarter

// Per-spin LDS pool, all regions coexist; HTQ is DOUBLE-buffered (R18):
//   s1e[160] @ 0, G[5][324] @ 160..1780, HTQ[2][16][124] @ 1780..5748
// Pool/spin = 22992 B -> block total ~46.1 KB -> 3 WGs/CU by LDS.
#define POOL_WORDS (160 + NPER * RS + 2 * KQ * HTS)

typedef float v2f __attribute__((ext_vector_type(2)));
typedef float v4f __attribute__((ext_vector_type(4)));

// Packed fp32 FMA (VOP3P), bit-identical to scalar v_fma pairs (R12-validated).
#define PK_FMA_LO(acc, hp, wp) \
    asm("v_pk_fma_f32 %0, %1, %2, %0 op_sel_hi:[1,0,1]" : "+v"(acc) : "v"(hp), "v"(wp))
#define PK_FMA_HI(acc, hp, wp) \
    asm("v_pk_fma_f32 %0, %1, %2, %0 op_sel:[0,1,0] op_sel_hi:[1,1,1]" : "+v"(acc) : "v"(hp), "v"(wp))

// tanh(x) = 1 - 2*rcp(exp(2x)+1): ~1-2 ulp, exact at saturation. Validated R5-R15.
__device__ __forceinline__ float fast_tanh(float x) {
    float e = __expf(2.0f * x);
    return 1.0f - 2.0f * __builtin_amdgcn_rcpf(e + 1.0f);
}

__device__ __forceinline__ unsigned pick_remove(unsigned& el, int d) {
    unsigned v = (el >> (4 * d)) & 0xFu;
    unsigned low = el & ((1u << (4 * d)) - 1u);
    el = low | ((el >> (4 * (d + 1))) << (4 * d));
    return v;
}

// ---------------- fused: one block per batch element, 4 waves = 2 spin-pairs ----------------
// R18 = R17 + double-buffered HTQ. R17 showed occupancy is NOT the lever (30% vs 20%,
// dur 104 vs 100): the cost is stage-3 phase serialization. Double-buffering gives
//   park(0); bar; {park(q+1) || gemm(q)}; bar; ...
// -> 4 stage-3 barriers (vs R17's 8) and, crucially, each region mixes the latency-
// bound tanh/G-read chain (park) with the independent pk_fma stream (gemm) so the
// scheduler fills chain stalls within a wave. k+1 prefetch restored (R10-validated,
// dropped in R17 = part of its regression). Buffer rotation race-free: park(q+1)
// writes the buffer gemm(q) is not reading; reuse only after the region barrier.
// hdot order ascending-cc -> per-element arithmetic bit-identical to R13/R17.
__global__ __launch_bounds__(256, 1) __attribute__((amdgpu_num_vgpr(128)))
void antisym_fused(
    const float* __restrict__ elec_pos, const float* __restrict__ ion_pos,
    const float* __restrict__ bf_w, const float* __restrict__ bf_b,
    const float* __restrict__ w0, const float* __restrict__ b0,
    const float* __restrict__ w1, const float* __restrict__ b1,
    const float* __restrict__ w2, const float* __restrict__ jk,
    float* __restrict__ out, int B)
{
    const int b = blockIdx.x;
    const int t = threadIdx.x;
    const int s = t >> 7;                   // spin: waves 0-1 -> 0, waves 2-3 -> 1
    const int ts = t & 127;                 // thread within the spin-pair
    const int wave = (t >> 6) & 1;          // wave within the spin-pair
    const int lane = t & 63;

    __shared__ __align__(16) float pool[NSPIN][POOL_WORDS];   // 2 x 22992 B
    __shared__ double red_h[NSPIN][2];
    __shared__ double red_j[NSPIN][2];
    __shared__ float jterm[2 * NELEC];

    float* s1e = pool[s];                                     // [160]
    #define GROW(j)       (pool[s] + 160 + (j) * RS)          // G[j][.]
    #define HTQROW(bf, k) (pool[s] + 160 + NPER * RS + (bf) * (KQ * HTS) + (k) * HTS)

    // ---- stage 1: stream_1e = tanh(feats @ bf_w + bf_b), this spin's 5 electrons ----
    const float* ep = elec_pos + (b * NELEC + s * NPER) * DIM;
    const float i0x = ion_pos[0], i0y = ion_pos[1], i0z = ion_pos[2];
    const float i1x = ion_pos[3], i1y = ion_pos[4], i1z = ion_pos[5];
    for (int idx = ts; idx < NPER * DP; idx += 128) {
        int j = idx >> 5, c = idx & 31;
        float ex = ep[j * 3 + 0], ey = ep[j * 3 + 1], ez = ep[j * 3 + 2];
        float dx0 = ex - i0x, dy0 = ey - i0y, dz0 = ez - i0z;
        float dx1 = ex - i1x, dy1 = ey - i1y, dz1 = ez - i1z;
        float n0 = sqrtf(dx0 * dx0 + dy0 * dy0 + dz0 * dz0);
        float n1 = sqrtf(dx1 * dx1 + dy1 * dy1 + dz1 * dz1);
        float acc = bf_b[c];
        acc += dx0 * bf_w[0 * DP + c];
        acc += dy0 * bf_w[1 * DP + c];
        acc += dz0 * bf_w[2 * DP + c];
        acc += dx1 * bf_w[3 * DP + c];
        acc += dy1 * bf_w[4 * DP + c];
        acc += dz1 * bf_w[5 * DP + c];
        acc += n0 * bf_w[6 * DP + c];
        acc += n1 * bf_w[7 * DP + c];
        s1e[idx] = fast_tanh(acc);
    }
    // jastrow terms (combine's exact per-term math; summed e-major by t0 later)
    if (t < 2 * NELEC) {
        int e = t >> 1, ion = t & 1;
        const float* epb = elec_pos + b * NELEC * DIM;
        float ex = epb[e * 3 + 0], ey = epb[e * 3 + 1], ez = epb[e * 3 + 2];
        float ix = ion_pos[ion * 3 + 0], iy = ion_pos[ion * 3 + 1], iz = ion_pos[ion * 3 + 2];
        float dx = ex - ix, dy = ey - iy, dz = ez - iz;
        jterm[t] = jk[ion] * sqrtf(dx * dx + dy * dy + dz * dz);
    }
    __syncthreads();

    // ---- stage 2: G[j][i*64+c] = s1e[j][:] @ w0[s][32i:32i+32, c] ----
    // Slice-outer with wcol[32] in registers (R14): 96 global loads/wave.
    const float* w0s = w0 + s * (NPER * DP) * NDENSE;   // [160][64]
    #pragma unroll
    for (int m = 0; m < 3; m++) {
        const int i = wave + 2 * m;         // wave0: i=0,2,4  wave1: i=1,3 (m=2 skipped)
        if (i < NPER) {                     // wave-uniform branch
            float wcol[DP];
            #pragma unroll
            for (int k = 0; k < DP; k++) wcol[k] = w0s[(i * DP + k) * NDENSE + lane];
            #pragma unroll
            for (int j = 0; j < NPER; j++) {
                float acc = 0.f;
                #pragma unroll
                for (int q = 0; q < 8; q++) {
                    float4 sv = *(const float4*)(s1e + j * DP + q * 4);   // LDS broadcast
                    acc += sv.x * wcol[q * 4 + 0];
                    acc += sv.y * wcol[q * 4 + 1];
                    acc += sv.z * wcol[q * 4 + 2];
                    acc += sv.w * wcol[q * 4 + 3];
                }
                GROW(j)[i * NDENSE + lane] = acc;
            }
        }
    }
    __syncthreads();

    const float* b0s = b0 + s * NDENSE;
    const float* w2s = w2 + s * NDENSE;     // w2 is [s][64][1]
    const float* b1s = b1 + s * NDENSE;
    const float* w1s = w1 + s * NDENSE * NDENSE;

    // ---- stage 3: lane = perm (park) pipelined with 8x8-tile GEMM, dbuf HTQ ----
    const int pid = wave * 60 + lane;
    float sign = 0.f;
    int p0 = 0, p1 = 0, p2 = 0, p3 = 0, p4 = 0;
    if (lane < 60) {
        int p = pid;
        unsigned el = 0x43210u;
        int d0 = p / 24; p -= d0 * 24;
        int d1 = p / 6;  p -= d1 * 6;
        int d2 = p / 2;  p -= d2 * 2;
        int d3 = p;
        p0 = pick_remove(el, d0);
        p1 = pick_remove(el, d1);
        p2 = pick_remove(el, d2);
        p3 = pick_remove(el, d3);
        p4 = el & 0xF;
        sign = ((d0 + d1 + d2 + d3) & 1) ? -1.f : 1.f;
    }
    const float* g0 = GROW(p0) + 0 * NDENSE;
    const float* g1 = GROW(p1) + 1 * NDENSE;
    const float* g2 = GROW(p2) + 2 * NDENSE;
    const float* g3 = GROW(p3) + 3 * NDENSE;
    const float* g4 = GROW(p4) + 4 * NDENSE;

    const int pg = lane >> 3, jg = lane & 7;
    const int pb = wave ? (56 + 8 * pg) : (8 * pg);
    const float* wgp = w1s + 8 * jg;        // this lane's j-octet in w1 row k

    v2f vp[4][8];
    #pragma unroll
    for (int ip = 0; ip < 4; ip++)
        #pragma unroll
        for (int r = 0; r < 8; r++) vp[ip][r] = (v2f)(0.f);

    float hdot = 0.f;

    // park quarter qq into HTQ buffer bf (h written straight to LDS; ascending cc)
    auto park_quarter = [&](int qq, int bf) {
        #pragma unroll
        for (int c = 0; c < 4; c++) {
            const int cc = qq * 4 + c;
            float4 a = *(const float4*)(b0s + cc * 4);                    // uniform
            float4 q;
            q = *(const float4*)(g0 + cc * 4); a.x += q.x; a.y += q.y; a.z += q.z; a.w += q.w;
            q = *(const float4*)(g1 + cc * 4); a.x += q.x; a.y += q.y; a.z += q.z; a.w += q.w;
            q = *(const float4*)(g2 + cc * 4); a.x += q.x; a.y += q.y; a.z += q.z; a.w += q.w;
            q = *(const float4*)(g3 + cc * 4); a.x += q.x; a.y += q.y; a.z += q.z; a.w += q.w;
            q = *(const float4*)(g4 + cc * 4); a.x += q.x; a.y += q.y; a.z += q.z; a.w += q.w;
            float t0 = fast_tanh(a.x), t1 = fast_tanh(a.y), t2 = fast_tanh(a.z), t3 = fast_tanh(a.w);
            if (lane < 60) {
                HTQROW(bf, c * 4 + 0)[pid] = t0;   // b32, consecutive pids -> free
                HTQROW(bf, c * 4 + 1)[pid] = t1;
                HTQROW(bf, c * 4 + 2)[pid] = t2;
                HTQROW(bf, c * 4 + 3)[pid] = t3;
            }
            hdot += t0 * w2s[cc * 4 + 0] + t1 * w2s[cc * 4 + 1]
                  + t2 * w2s[cc * 4 + 2] + t3 * w2s[cc * 4 + 3];
        }
    };

    // 16 k-steps of V[120x64] = H @ W1 from HTQ buffer bf (k+1 prefetch, R10)
    auto gemm_quarter = [&](int qq, int bf) {
        const float* hb0 = HTQROW(bf, 0);
        v4f ha_n = *(const v4f*)(hb0 + pb);
        v4f hb_n = *(const v4f*)(hb0 + pb + 4);
        v4f wa_n = *(const v4f*)(wgp + (qq * KQ) * NDENSE);
        v4f wb_n = *(const v4f*)(wgp + (qq * KQ) * NDENSE + 4);
        #pragma unroll 4
        for (int kk = 0; kk < KQ; kk++) {
            const v4f ha = ha_n, hb = hb_n, wa = wa_n, wb = wb_n;
            if (kk + 1 < KQ) {
                ha_n = *(const v4f*)(hb0 + (kk + 1) * HTS + pb);
                hb_n = *(const v4f*)(hb0 + (kk + 1) * HTS + pb + 4);
                wa_n = *(const v4f*)(wgp + (qq * KQ + kk + 1) * NDENSE);
                wb_n = *(const v4f*)(wgp + (qq * KQ + kk + 1) * NDENSE + 4);
            }
            v2f hp[4] = {ha.xy, ha.zw, hb.xy, hb.zw};   // perm pairs
            v2f wp[4] = {wa.xy, wa.zw, wb.xy, wb.zw};   // j pairs
            #pragma unroll
            for (int ip = 0; ip < 4; ip++) {
                PK_FMA_LO(vp[ip][0], hp[ip], wp[0]);
                PK_FMA_HI(vp[ip][1], hp[ip], wp[0]);
                PK_FMA_LO(vp[ip][2], hp[ip], wp[1]);
                PK_FMA_HI(vp[ip][3], hp[ip], wp[1]);
                PK_FMA_LO(vp[ip][4], hp[ip], wp[2]);
                PK_FMA_HI(vp[ip][5], hp[ip], wp[2]);
                PK_FMA_LO(vp[ip][6], hp[ip], wp[3]);
                PK_FMA_HI(vp[ip][7], hp[ip], wp[3]);
            }
        }
    };

    park_quarter(0, 0);
    __syncthreads();                        // HTQ[0] visible
    #pragma unroll
    for (int qq = 0; qq < 4; qq++) {
        if (qq < 3) park_quarter(qq + 1, (qq + 1) & 1);   // writes the OTHER buffer
        gemm_quarter(qq, qq & 1);                          // reads current buffer
        __syncthreads();                    // releases buf qq&1 for park(qq+2); buf (qq+1)&1 ready
    }

    double dvh = (double)(sign * hdot);     // sign=0 for lanes 60-63
    #pragma unroll
    for (int off = 32; off > 0; off >>= 1) dvh += __shfl_down(dvh, off, 64);
    if (lane == 0) red_h[s][wave] = dvh;

    // epilogue: lanesum = sum_i sgn_i * sum_r tanh(v[i][r]+b1[j]) * w2[j]
    float4 b1a = *(const float4*)(b1s + 8 * jg);
    float4 b1b = *(const float4*)(b1s + 8 * jg + 4);
    float4 w2a = *(const float4*)(w2s + 8 * jg);
    float4 w2b = *(const float4*)(w2s + 8 * jg + 4);
    const float b1v[8] = {b1a.x, b1a.y, b1a.z, b1a.w, b1b.x, b1b.y, b1b.z, b1b.w};
    const float w2v[8] = {w2a.x, w2a.y, w2a.z, w2a.w, w2b.x, w2b.y, w2b.z, w2b.w};

    float lanesum = 0.f;
    #pragma unroll
    for (int i = 0; i < 8; i++) {
        int p = pb + i;                      // Lehmer parity
        int d0 = p / 24;  int r0 = p - 24 * d0;
        int d1 = r0 / 6;  int r1 = r0 - 6 * d1;
        int d2 = r1 >> 1; int d3 = r1 & 1;
        float sgn = ((d0 + d1 + d2 + d3) & 1) ? -1.f : 1.f;
        if (wave == 1 && pg == 0) sgn = 0.f; // duplicate tile (perms 56-63)
        float si = 0.f;
        #pragma unroll
        for (int r = 0; r < 8; r++) {
            float vir = (i & 1) ? vp[i >> 1][r].y : vp[i >> 1][r].x;
            si = fmaf(fast_tanh(vir + b1v[r]), w2v[r], si);
        }
        lanesum = fmaf(sgn, si, lanesum);
    }

    double dvj = (double)lanesum;
    #pragma unroll
    for (int off = 32; off > 0; off >>= 1) dvj += __shfl_down(dvj, off, 64);
    if (lane == 0) red_j[s][wave] = dvj;
    __syncthreads();

    // ---- inline combine (R13-validated) ----
    if (t == 0) {
        float ps0 = (float)((red_h[0][0] + red_h[0][1]) + (red_j[0][0] + red_j[0][1]));
        float ps1 = (float)((red_h[1][0] + red_h[1][1]) + (red_j[1][0] + red_j[1][1]));
        float jas = 0.f;
        #pragma unroll
        for (int i = 0; i < 2 * NELEC; i++) jas += jterm[i];
        out[b] = logf(fabsf(ps0 * ps1)) - jas;
    }
    // b2 omitted: sum_p sign_p = 0 kills it exactly.
}

extern "C" void kernel_launch(void* const* d_in, const int* in_sizes, int n_in,
                              void* d_out, int out_size, void* d_ws, size_t ws_size,
                              hipStream_t stream) {
    const float* elec_pos = (const float*)d_in[0];
    const float* ion_pos  = (const float*)d_in[1];
    const float* bf_w     = (const float*)d_in[2];
    const float* bf_b     = (const float*)d_in[3];
    const float* w0       = (const float*)d_in[4];
    const float* b0       = (const float*)d_in[5];
    const float* w1       = (const float*)d_in[6];
    const float* b1       = (const float*)d_in[7];
    const float* w2       = (const float*)d_in[8];
    const float* jk       = (const float*)d_in[10];
    float* out = (float*)d_out;

    const int B = in_sizes[0] / (NELEC * DIM);   // 2048

    hipLaunchKernelGGL(antisym_fused,
                       dim3(B), dim3(256), 0, stream,
                       elec_pos, ion_pos, bf_w, bf_b, w0, b0, w1, b1, w2, jk, out, B);
}